// Round 4
// baseline (575.935 us; speedup 1.0000x reference)
//
#include <hip/hip_runtime.h>

#define MDIM 8192
#define NDIM 4096
#define KDIM 4096

typedef __attribute__((ext_vector_type(8))) short short8;    // 8 bf16 = 4 VGPRs
typedef __attribute__((ext_vector_type(4))) float floatx4;   // MFMA C/D

typedef const __attribute__((address_space(1))) unsigned int* gptr_t;
typedef __attribute__((address_space(3))) unsigned int* lptr_t;

// fp32 -> bf16 round-to-nearest-even (bit trick; NaN irrelevant here)
static __device__ __forceinline__ unsigned short f2bf(float f) {
    union { float f; unsigned int u; } a; a.f = f;
    unsigned int r = a.u + 0x7FFFu + ((a.u >> 16) & 1u);
    return (unsigned short)(r >> 16);
}

// ---- kernel 1: x (fp32) -> bf16, vectorized grid-stride (unchanged) ----
__global__ void cvt_x_kernel(const float* __restrict__ x, unsigned short* __restrict__ xb) {
    int idx = blockIdx.x * blockDim.x + threadIdx.x;
    int stride = gridDim.x * blockDim.x;
    const float4* x4 = (const float4*)x;
    ushort4* o4 = (ushort4*)xb;
    const int n4 = (MDIM * KDIM) / 4;
    for (int i = idx; i < n4; i += stride) {
        float4 v = x4[i];
        ushort4 o;
        o.x = f2bf(v.x); o.y = f2bf(v.y); o.z = f2bf(v.z); o.w = f2bf(v.w);
        o4[i] = o;
    }
}

// ---- kernel 2: W (fp32) -> sign(W) bf16 (+1/-1/0 exact), fused sum(|W|) (unchanged) ----
__global__ void cvt_w_kernel(const float* __restrict__ w, unsigned short* __restrict__ sb,
                             float* __restrict__ sum) {
    int idx = blockIdx.x * blockDim.x + threadIdx.x;
    int stride = gridDim.x * blockDim.x;
    const float4* w4 = (const float4*)w;
    ushort4* o4 = (ushort4*)sb;
    const int n4 = (NDIM * KDIM) / 4;
    float s = 0.f;
    for (int i = idx; i < n4; i += stride) {
        float4 v = w4[i];
        ushort4 o;
        o.x = (unsigned short)(v.x > 0.f ? 0x3F80 : (v.x < 0.f ? 0xBF80 : 0));
        o.y = (unsigned short)(v.y > 0.f ? 0x3F80 : (v.y < 0.f ? 0xBF80 : 0));
        o.z = (unsigned short)(v.z > 0.f ? 0x3F80 : (v.z < 0.f ? 0xBF80 : 0));
        o.w = (unsigned short)(v.w > 0.f ? 0x3F80 : (v.w < 0.f ? 0xBF80 : 0));
        s += fabsf(v.x) + fabsf(v.y) + fabsf(v.z) + fabsf(v.w);
        o4[i] = o;
    }
    #pragma unroll
    for (int off = 32; off > 0; off >>= 1) s += __shfl_down(s, off, 64);
    __shared__ float red[4];
    int lane = threadIdx.x & 63, wv = threadIdx.x >> 6;
    if (lane == 0) red[wv] = s;
    __syncthreads();
    if (threadIdx.x == 0) atomicAdd(sum, red[0] + red[1] + red[2] + red[3]);
}

// ============ kernel 3: 256x256-tile, 4-phase counted-vmcnt bf16 GEMM ============
// C[m,n] = scale * sum_k A[m,k]*B[n,k].  Buffer/staging/vmcnt schedule identical to
// the verified round-2 kernel (phase pairs merged).  ROUND-3 LESSON: the offset arg
// of __builtin_amdgcn_global_load_lds shifted the LDS-side address (LDS-DMA imm
// offset semantics) -> uninitialized LDS -> NaN.  All staging is offset=0 with
// per-phase pointer bumps instead (proven round-0/2 semantics).
// Buffers: As/Bs[buf], buf = parity*2 + khalf:
//   buf0 = par0 kh0, buf1 = par0 kh1, buf2 = par1 kh0, buf3 = par1 kh1.
// Staging pointers are pre-offset +96 elems after the prologue; each STAGE_AB
// stages at pointer+0 then bumps +32 elems, so per iter (tiles t=2it, t+1):
//   PI : read buf0; stage kh1pair(t+1)->buf3
//   PII: read buf1; stage kh0 (t+2)->buf0; vmcnt(4)  [tile t+1 resident]
//   PIII:read buf2; stage kh1pair(t+2)->buf1
//   PIV: read buf3; stage kh0 (t+3)->buf2; vmcnt(4)  [tile t+2 resident]
// Steady state: 12 outstanding at each vmcnt(4), retires the 8 oldest; 4 loads
// always in flight across barriers (never drains to 0 in-loop).  All waves run the
// same vmcnt+barrier sequence.  Peel: 1 stage (kh1(63) at pointer+0 = elem 4064),
// one vmcnt(0) drain.
// Swizzle (verified): LDS phys chunk p holds global chunk p^((row>>1)&3); read
// offset pk = (kc ^ ((fr>>1)&3))<<3.  Bank conflicts measured 0.

#define MEMBAR() asm volatile("" ::: "memory")
#define BARRIER() do { MEMBAR(); __builtin_amdgcn_s_barrier(); MEMBAR(); } while (0)
#define VMCNT4() asm volatile("s_waitcnt vmcnt(4)" ::: "memory")
#define VMCNT0() asm volatile("s_waitcnt vmcnt(0)" ::: "memory")
#define PRIO1() __builtin_amdgcn_s_setprio(1)
#define PRIO0() __builtin_amdgcn_s_setprio(0)

#define GLD(SRC, DST) \
    __builtin_amdgcn_global_load_lds((gptr_t)(SRC), (lptr_t)(DST), 16, 0, 0)

// prologue staging at explicit one-time offsets (no bump)
#define STAGE_AT(BUF, OFS) do { \
    GLD(pA0 + (OFS), &As[BUF][0]    + wvoff); \
    GLD(pA1 + (OFS), &As[BUF][4096] + wvoff); \
    GLD(pB0 + (OFS), &Bs[BUF][0]    + wvoff); \
    GLD(pB1 + (OFS), &Bs[BUF][4096] + wvoff); } while (0)

// steady-state staging: always at pointer+0, then bump +32 elems (64 B)
#define STAGE_AB(BUF) do { \
    GLD(pA0, &As[BUF][0]    + wvoff); \
    GLD(pA1, &As[BUF][4096] + wvoff); \
    GLD(pB0, &Bs[BUF][0]    + wvoff); \
    GLD(pB1, &Bs[BUF][4096] + wvoff); \
    pA0 += 32; pA1 += 32; pB0 += 32; pB1 += 32; } while (0)

template <int BUF>
static __device__ __forceinline__ void ld12(short8 (&af)[8], short8 (&bf)[4],
                                            const unsigned short* aB,
                                            const unsigned short* bB) {
    #pragma unroll
    for (int m = 0; m < 4; ++m) af[m] = *(const short8*)(aB + BUF * 8192 + m * 512);
    #pragma unroll
    for (int j = 0; j < 4; ++j) bf[j] = *(const short8*)(bB + BUF * 8192 + j * 512);
    #pragma unroll
    for (int m = 4; m < 8; ++m) af[m] = *(const short8*)(aB + BUF * 8192 + m * 512);
}

static __device__ __forceinline__ void mfma32(floatx4 (&acc)[8][4], const short8 (&af)[8],
                                              const short8 (&bf)[4]) {
    #pragma unroll
    for (int m = 0; m < 8; ++m)
        #pragma unroll
        for (int j = 0; j < 4; ++j)
            acc[m][j] = __builtin_amdgcn_mfma_f32_16x16x32_bf16(af[m], bf[j], acc[m][j], 0, 0, 0);
}

__global__ __launch_bounds__(512, 2) void gemm_kernel(
    const unsigned short* __restrict__ A,   // MDIM x KDIM bf16
    const unsigned short* __restrict__ B,   // NDIM x KDIM bf16 (sign weights)
    float* __restrict__ C,                  // MDIM x NDIM fp32
    const float* __restrict__ sum)          // sum(|W|); scale = sum / (N*K)
{
    __shared__ __align__(16) unsigned short As[4][8192];   // 64 KB
    __shared__ __align__(16) unsigned short Bs[4][8192];   // 64 KB

    const int t = threadIdx.x;
    const int lane = t & 63;
    const int wv = t >> 6;            // wave 0..7
    const int wr = wv >> 2;           // wave M-row 0..1 -> 128-row slab
    const int wc = wv & 3;            // wave N-col 0..3 -> 64-col slab
    const int wvoff = wv * 512;       // LDS staging slice (elements)

    // T1: XCD swizzle. 512 blocks, 8 XCDs, 64 blocks/XCD = 4 tile-rows x 16 cols.
    const int bid = blockIdx.x;
    const int lin = (bid & 7) * 64 + (bid >> 3);
    const int m0 = (lin >> 4) * 256;
    const int n0 = (lin & 15) * 256;

    // fragment-read bases (invariant): lane reads row base+fr, k-chunk kc;
    // phys chunk = kc ^ ((fr>>1)&3) since all row bases are %16==0.
    const int fr = lane & 15;
    const int kc = lane >> 4;
    const int pk = ((kc ^ ((fr >> 1) & 3)) << 3);
    const unsigned short* aB = &As[0][0] + (wr * 128 + fr) * 32 + pk;
    const unsigned short* bB = &Bs[0][0] + (wc * 64 + fr) * 32 + pk;

    // staging sources: thread t covers row t>>2 (and +128), chunk (t&3)^((t>>3)&3)
    const int srow = t >> 2;
    const int schunk = ((t & 3) ^ ((t >> 3) & 3)) << 3;
    const unsigned short* pA0 = A + (size_t)(m0 + srow) * KDIM + schunk;
    const unsigned short* pA1 = pA0 + (size_t)128 * KDIM;
    const unsigned short* pB0 = B + (size_t)(n0 + srow) * KDIM + schunk;
    const unsigned short* pB1 = pB0 + (size_t)128 * KDIM;

    floatx4 acc[8][4] = {};
    short8 af[8];
    short8 bf[4];

    // ---- prologue: tile0 (kh0+kh1) + tile1 kh0; leave tile1 kh0 (4 loads) in flight
    STAGE_AT(0, 0);     // kh0(0)
    STAGE_AT(1, 32);    // kh1(0)
    STAGE_AT(2, 64);    // kh0(1)
    pA0 += 96; pA1 += 96; pB0 += 96; pB1 += 96;   // all further stages at +0
    VMCNT4();            // tile0 resident
    BARRIER();

    // ---- main loop: 31 iterations of 2 K-tiles (4 stages/iter -> +128 elems/iter)
    #pragma unroll 1
    for (int it = 0; it < 31; ++it) {
        // PI: tile t, kb0
        ld12<0>(af, bf, aB, bB);
        STAGE_AB(3);                      // kh1pair(t+1)
        BARRIER(); PRIO1(); mfma32(acc, af, bf); PRIO0(); BARRIER();
        // PII: tile t, kb1
        ld12<1>(af, bf, aB, bB);
        STAGE_AB(0);                      // kh0(t+2)
        VMCNT4();                          // tile t+1 fully resident
        BARRIER(); PRIO1(); mfma32(acc, af, bf); PRIO0(); BARRIER();
        // PIII: tile t+1, kb0
        ld12<2>(af, bf, aB, bB);
        STAGE_AB(1);                      // kh1pair(t+2)
        BARRIER(); PRIO1(); mfma32(acc, af, bf); PRIO0(); BARRIER();
        // PIV: tile t+1, kb1
        ld12<3>(af, bf, aB, bB);
        STAGE_AB(2);                      // kh0(t+3)
        VMCNT4();                          // tile t+2 fully resident
        BARRIER(); PRIO1(); mfma32(acc, af, bf); PRIO0(); BARRIER();
    }

    // ---- peel: tiles 62, 63 (pointers now at elem 96 + 31*128 = 4064 = kh1(63))
    ld12<0>(af, bf, aB, bB);
    STAGE_AB(3);                          // kh1pair(63) at pointer+0
    BARRIER(); PRIO1(); mfma32(acc, af, bf); PRIO0(); BARRIER();
    ld12<1>(af, bf, aB, bB);
    VMCNT0();                              // drain: tile 63 resident
    BARRIER(); PRIO1(); mfma32(acc, af, bf); PRIO0(); BARRIER();
    ld12<2>(af, bf, aB, bB);
    BARRIER(); PRIO1(); mfma32(acc, af, bf); PRIO0(); BARRIER();
    ld12<3>(af, bf, aB, bB);
    BARRIER(); PRIO1(); mfma32(acc, af, bf); PRIO0();

    // ---- epilogue: C/D layout col = lane&15, row = (lane>>4)*4 + reg
    const float scale = sum[0] * (1.0f / (float)((size_t)NDIM * KDIM));
    const int r0w = (lane >> 4) << 2;
    const int cB = n0 + wc * 64 + (lane & 15);
    #pragma unroll
    for (int m = 0; m < 8; ++m) {
        #pragma unroll
        for (int r = 0; r < 4; ++r) {
            const int row = m0 + wr * 128 + m * 16 + r0w + r;
            float* crow = C + (size_t)row * NDIM + cB;
            #pragma unroll
            for (int nn = 0; nn < 4; ++nn)
                crow[nn * 16] = acc[m][nn][r] * scale;
        }
    }
}

extern "C" void kernel_launch(void* const* d_in, const int* in_sizes, int n_in,
                              void* d_out, int out_size, void* d_ws, size_t ws_size,
                              hipStream_t stream) {
    const float* x = (const float*)d_in[0];   // 8192 x 4096 fp32
    const float* w = (const float*)d_in[1];   // 4096 x 4096 fp32
    float* out = (float*)d_out;               // 8192 x 4096 fp32

    // workspace layout: [x_bf16: 67,108,864 B][signW_bf16: 33,554,432 B][sum: 4 B]
    unsigned short* xb = (unsigned short*)d_ws;
    unsigned short* wb = (unsigned short*)((char*)d_ws + (size_t)MDIM * KDIM * 2);
    float* sum = (float*)((char*)d_ws + (size_t)MDIM * KDIM * 2 + (size_t)NDIM * KDIM * 2);

    hipMemsetAsync(sum, 0, sizeof(float), stream);  // ws is poisoned 0xAA each run
    cvt_x_kernel<<<2048, 256, 0, stream>>>(x, xb);
    cvt_w_kernel<<<2048, 256, 0, stream>>>(w, wb, sum);

    gemm_kernel<<<dim3(512), dim3(512), 0, stream>>>(xb, wb, out, sum);
}

// Round 6
// 537.650 us; speedup vs baseline: 1.0712x; 1.0712x over previous
//
#include <hip/hip_runtime.h>

#define MDIM 8192
#define NDIM 4096
#define KDIM 4096

typedef __attribute__((ext_vector_type(8))) short short8;    // 8 bf16 = 4 VGPRs
typedef __attribute__((ext_vector_type(4))) float floatx4;   // MFMA C/D

typedef const __attribute__((address_space(1))) unsigned int* gptr_t;
typedef __attribute__((address_space(3))) unsigned int* lptr_t;

// fp32 -> bf16 round-to-nearest-even (bit trick; NaN irrelevant here)
static __device__ __forceinline__ unsigned short f2bf(float f) {
    union { float f; unsigned int u; } a; a.f = f;
    unsigned int r = a.u + 0x7FFFu + ((a.u >> 16) & 1u);
    return (unsigned short)(r >> 16);
}

// ---- kernel 1: x (fp32) -> bf16, vectorized grid-stride (unchanged) ----
__global__ void cvt_x_kernel(const float* __restrict__ x, unsigned short* __restrict__ xb) {
    int idx = blockIdx.x * blockDim.x + threadIdx.x;
    int stride = gridDim.x * blockDim.x;
    const float4* x4 = (const float4*)x;
    ushort4* o4 = (ushort4*)xb;
    const int n4 = (MDIM * KDIM) / 4;
    for (int i = idx; i < n4; i += stride) {
        float4 v = x4[i];
        ushort4 o;
        o.x = f2bf(v.x); o.y = f2bf(v.y); o.z = f2bf(v.z); o.w = f2bf(v.w);
        o4[i] = o;
    }
}

// ---- kernel 2: W (fp32) -> sign(W) bf16 (+1/-1/0 exact), fused sum(|W|) (unchanged) ----
__global__ void cvt_w_kernel(const float* __restrict__ w, unsigned short* __restrict__ sb,
                             float* __restrict__ sum) {
    int idx = blockIdx.x * blockDim.x + threadIdx.x;
    int stride = gridDim.x * blockDim.x;
    const float4* w4 = (const float4*)w;
    ushort4* o4 = (ushort4*)sb;
    const int n4 = (NDIM * KDIM) / 4;
    float s = 0.f;
    for (int i = idx; i < n4; i += stride) {
        float4 v = w4[i];
        ushort4 o;
        o.x = (unsigned short)(v.x > 0.f ? 0x3F80 : (v.x < 0.f ? 0xBF80 : 0));
        o.y = (unsigned short)(v.y > 0.f ? 0x3F80 : (v.y < 0.f ? 0xBF80 : 0));
        o.z = (unsigned short)(v.z > 0.f ? 0x3F80 : (v.z < 0.f ? 0xBF80 : 0));
        o.w = (unsigned short)(v.w > 0.f ? 0x3F80 : (v.w < 0.f ? 0xBF80 : 0));
        s += fabsf(v.x) + fabsf(v.y) + fabsf(v.z) + fabsf(v.w);
        o4[i] = o;
    }
    #pragma unroll
    for (int off = 32; off > 0; off >>= 1) s += __shfl_down(s, off, 64);
    __shared__ float red[4];
    int lane = threadIdx.x & 63, wv = threadIdx.x >> 6;
    if (lane == 0) red[wv] = s;
    __syncthreads();
    if (threadIdx.x == 0) atomicAdd(sum, red[0] + red[1] + red[2] + red[3]);
}

// ====== kernel 3: 256x256-tile, 8-phase, register-prefetch-pipelined bf16 GEMM ======
// C[m,n] = scale * sum_k A[m,k]*B[n,k].
// R2 (8 fat-read phases, lockstep): 291us, MfmaUtil 40.  R4 (4 merged): 311us, 38.
// Model: fragment ds_reads issued just-before-barrier + waited just-after =>
// LDS service (~2000cyc/K-tile/CU) serializes with MFMA (2482cyc).  Fix: double-
// buffered fragment register sets; phase p issues phase p+1's ds_reads BEFORE its
// MFMA cluster, so the 16-MFMA burst hides the LDS service (T3 fine-interleave).
// R5 LESSON: __launch_bounds__(512,2) forced a 128-VGPR ceiling (m69: 16 waves/CU
// needs <=128 VGPR) onto ~220 live regs -> inner-loop scratch spills -> timeout.
// 128KB LDS caps residency at 1 block/CU anyway, so declare (512,1): full register
// budget at the SAME actual occupancy (m201's exact config).
// Buffers (16KB each): buf0=par0 kh0, buf1=par0 kh1, buf2=par1 kh0, buf3=par1 kh1.
// Stages (2 gloads/phase, bump-pointer): p1:buf3.A p2:buf3.B p3:buf0.A
// p4:buf0.B+vmcnt(4) p5:buf1.A p6:buf1.B p7:buf2.A p8:buf2.B+vmcnt(4).
// vmcnt audit (steady, 12 outstanding at p4/p8, retire 8): p4 proves buf2(kh0 t+1)
// + buf3(kh1 t+1) resident; p8 proves buf0(kh0 t+2) + buf1(kh1 t+2).  Every e-read
// follows its buffer's proving vmcnt+barrier; every overwrite is >=1 barrier after
// the consumer-wait of the last ds_read of old contents; regset WAR gaps are one
// full phase.  Peel: one stage + single vmcnt(0) drain.
// Swizzle (verified R0/R2/R4): LDS phys chunk p holds global chunk p^((row>>1)&3);
// read offset pk = (kc ^ ((fr>>1)&3))<<3.  Bank conflicts measured 0.
// T1 XCD swizzle: 64 contiguous blocks per XCD.

#define MEMBAR() asm volatile("" ::: "memory")
#define BARRIER() do { MEMBAR(); __builtin_amdgcn_s_barrier(); MEMBAR(); } while (0)
#define VMCNT4() asm volatile("s_waitcnt vmcnt(4)" ::: "memory")
#define VMCNT0() asm volatile("s_waitcnt vmcnt(0)" ::: "memory")
#define PRIO1() __builtin_amdgcn_s_setprio(1)
#define PRIO0() __builtin_amdgcn_s_setprio(0)
#define SCHEDB() __builtin_amdgcn_sched_barrier(0)

#define GLD(SRC, DST) \
    __builtin_amdgcn_global_load_lds((gptr_t)(SRC), (lptr_t)(DST), 16, 0, 0)

// stage half-of-a-half: A-pair or B-pair (2 gloads/wave), then bump +32 elems
#define STAGE_A(BUF) do { \
    GLD(pA0, &As[BUF][0]    + wvoff); \
    GLD(pA1, &As[BUF][4096] + wvoff); \
    pA0 += 32; pA1 += 32; } while (0)
#define STAGE_B(BUF) do { \
    GLD(pB0, &Bs[BUF][0]    + wvoff); \
    GLD(pB1, &Bs[BUF][4096] + wvoff); \
    pB0 += 32; pB1 += 32; } while (0)

template <int BUF>
static __device__ __forceinline__ void ld_af8(short8 (&af)[8], const unsigned short* aB) {
    #pragma unroll
    for (int m = 0; m < 8; ++m) af[m] = *(const short8*)(aB + BUF * 8192 + m * 512);
}
template <int BUF, int NP>
static __device__ __forceinline__ void ld_bf2(short8 (&bf)[2], const unsigned short* bB) {
    bf[0] = *(const short8*)(bB + BUF * 8192 + NP * 1024);
    bf[1] = *(const short8*)(bB + BUF * 8192 + NP * 1024 + 512);
}
template <int NP>
static __device__ __forceinline__ void mfma16(floatx4 (&acc)[8][4], const short8 (&af)[8],
                                              const short8 (&bf)[2]) {
    #pragma unroll
    for (int m = 0; m < 8; ++m) {
        acc[m][NP * 2]     = __builtin_amdgcn_mfma_f32_16x16x32_bf16(af[m], bf[0], acc[m][NP * 2], 0, 0, 0);
        acc[m][NP * 2 + 1] = __builtin_amdgcn_mfma_f32_16x16x32_bf16(af[m], bf[1], acc[m][NP * 2 + 1], 0, 0, 0);
    }
}

__global__ __launch_bounds__(512, 1) void gemm_kernel(
    const unsigned short* __restrict__ A,   // MDIM x KDIM bf16
    const unsigned short* __restrict__ B,   // NDIM x KDIM bf16 (sign weights)
    float* __restrict__ C,                  // MDIM x NDIM fp32
    const float* __restrict__ sum)          // sum(|W|); scale = sum / (N*K)
{
    __shared__ __align__(16) unsigned short As[4][8192];   // 64 KB
    __shared__ __align__(16) unsigned short Bs[4][8192];   // 64 KB

    const int t = threadIdx.x;
    const int lane = t & 63;
    const int wv = t >> 6;            // wave 0..7
    const int wr = wv >> 2;           // wave M-row 0..1 -> 128-row slab
    const int wc = wv & 3;            // wave N-col 0..3 -> 64-col slab
    const int wvoff = wv * 512;       // LDS staging slice (elements)

    // T1: XCD swizzle. 512 blocks, 8 XCDs, 64 blocks/XCD = 4 tile-rows x 16 cols.
    const int bid = blockIdx.x;
    const int lin = (bid & 7) * 64 + (bid >> 3);
    const int m0 = (lin >> 4) * 256;
    const int n0 = (lin & 15) * 256;

    // fragment-read bases (invariant)
    const int fr = lane & 15;
    const int kc = lane >> 4;
    const int pk = ((kc ^ ((fr >> 1) & 3)) << 3);
    const unsigned short* aB = &As[0][0] + (wr * 128 + fr) * 32 + pk;
    const unsigned short* bB = &Bs[0][0] + (wc * 64 + fr) * 32 + pk;

    // staging sources: thread t covers row t>>2 (and +128), chunk (t&3)^((t>>3)&3)
    const int srow = t >> 2;
    const int schunk = ((t & 3) ^ ((t >> 3) & 3)) << 3;
    const unsigned short* pA0 = A + (size_t)(m0 + srow) * KDIM + schunk;
    const unsigned short* pA1 = pA0 + (size_t)128 * KDIM;
    const unsigned short* pB0 = B + (size_t)(n0 + srow) * KDIM + schunk;
    const unsigned short* pB1 = pB0 + (size_t)128 * KDIM;

    floatx4 acc[8][4] = {};
    short8 afA[8], afB[8];   // A-fragment double buffer (alternates per k-half)
    short8 bfX[2], bfY[2];   // B-fragment double buffer (alternates per phase)

    // ---- prologue: stage buf0@0, buf1@+32, buf2@+64; leave buf2's 4 in flight
    STAGE_A(0); STAGE_B(0);     // kh0(0)   (bump -> +32)
    STAGE_A(1); STAGE_B(1);     // kh1(0)   (bump -> +64)
    STAGE_A(2); STAGE_B(2);     // kh0(1)   (bump -> +96)
    VMCNT4();                    // buf0, buf1 resident
    BARRIER();
    ld_af8<0>(afA, aB);          // prefetch p1 fragments (tile0 kh0)
    ld_bf2<0, 0>(bfX, bB);

    // ---- main loop: 31 iterations of 2 K-tiles (tiles t=2it, t+1)
    #pragma unroll 1
    for (int it = 0; it < 31; ++it) {
        // p1: MFMA buf0/n01 (afA,bfX); prefetch bfY<-buf0/n23; stage buf3.A
        STAGE_A(3);
        BARRIER();
        ld_bf2<0, 1>(bfY, bB); SCHEDB();
        PRIO1(); mfma16<0>(acc, afA, bfX); PRIO0();
        BARRIER();
        // p2: MFMA buf0/n23 (afA,bfY); prefetch afB,bfX<-buf1; stage buf3.B
        STAGE_B(3);
        BARRIER();
        ld_af8<1>(afB, aB); ld_bf2<1, 0>(bfX, bB); SCHEDB();
        PRIO1(); mfma16<1>(acc, afA, bfY); PRIO0();
        BARRIER();
        // p3: MFMA buf1/n01 (afB,bfX); prefetch bfY<-buf1/n23; stage buf0.A
        STAGE_A(0);
        BARRIER();
        ld_bf2<1, 1>(bfY, bB); SCHEDB();
        PRIO1(); mfma16<0>(acc, afB, bfX); PRIO0();
        BARRIER();
        // p4: MFMA buf1/n23 (afB,bfY); prefetch afA,bfX<-buf2; stage buf0.B +vmcnt
        STAGE_B(0);
        VMCNT4();                          // proves buf2 + buf3 resident
        BARRIER();
        ld_af8<2>(afA, aB); ld_bf2<2, 0>(bfX, bB); SCHEDB();
        PRIO1(); mfma16<1>(acc, afB, bfY); PRIO0();
        BARRIER();
        // p5: MFMA buf2/n01 (afA,bfX); prefetch bfY<-buf2/n23; stage buf1.A
        STAGE_A(1);
        BARRIER();
        ld_bf2<2, 1>(bfY, bB); SCHEDB();
        PRIO1(); mfma16<0>(acc, afA, bfX); PRIO0();
        BARRIER();
        // p6: MFMA buf2/n23 (afA,bfY); prefetch afB,bfX<-buf3; stage buf1.B
        STAGE_B(1);
        BARRIER();
        ld_af8<3>(afB, aB); ld_bf2<3, 0>(bfX, bB); SCHEDB();
        PRIO1(); mfma16<1>(acc, afA, bfY); PRIO0();
        BARRIER();
        // p7: MFMA buf3/n01 (afB,bfX); prefetch bfY<-buf3/n23; stage buf2.A
        STAGE_A(2);
        BARRIER();
        ld_bf2<3, 1>(bfY, bB); SCHEDB();
        PRIO1(); mfma16<0>(acc, afB, bfX); PRIO0();
        BARRIER();
        // p8: MFMA buf3/n23 (afB,bfY); prefetch afA,bfX<-buf0(t+2); stage buf2.B +vmcnt
        STAGE_B(2);
        VMCNT4();                          // proves buf0 + buf1 (t+2) resident
        BARRIER();
        ld_af8<0>(afA, aB); ld_bf2<0, 0>(bfX, bB); SCHEDB();
        PRIO1(); mfma16<1>(acc, afB, bfY); PRIO0();
        BARRIER();
    }

    // ---- peel: tiles 62,63. Entry: buf2=kh0(63) in flight (4); afA/bfX hold buf0.
    STAGE_A(3);                            // kh1(63).A  (pA at 4064)
    BARRIER();
    ld_bf2<0, 1>(bfY, bB); SCHEDB();
    PRIO1(); mfma16<0>(acc, afA, bfX); PRIO0();
    BARRIER();
    STAGE_B(3);                            // kh1(63).B
    BARRIER();
    ld_af8<1>(afB, aB); ld_bf2<1, 0>(bfX, bB); SCHEDB();
    PRIO1(); mfma16<1>(acc, afA, bfY); PRIO0();
    BARRIER();
    BARRIER();
    ld_bf2<1, 1>(bfY, bB); SCHEDB();
    PRIO1(); mfma16<0>(acc, afB, bfX); PRIO0();
    BARRIER();
    VMCNT0();                              // drain: buf2 + buf3 (tile 63) resident
    BARRIER();
    ld_af8<2>(afA, aB); ld_bf2<2, 0>(bfX, bB); SCHEDB();
    PRIO1(); mfma16<1>(acc, afB, bfY); PRIO0();
    BARRIER();
    BARRIER();
    ld_bf2<2, 1>(bfY, bB); SCHEDB();
    PRIO1(); mfma16<0>(acc, afA, bfX); PRIO0();
    BARRIER();
    BARRIER();
    ld_af8<3>(afB, aB); ld_bf2<3, 0>(bfX, bB); SCHEDB();
    PRIO1(); mfma16<1>(acc, afA, bfY); PRIO0();
    BARRIER();
    BARRIER();
    ld_bf2<3, 1>(bfY, bB); SCHEDB();
    PRIO1(); mfma16<0>(acc, afB, bfX); PRIO0();
    BARRIER();
    PRIO1(); mfma16<1>(acc, afB, bfY); PRIO0();

    // ---- epilogue: C/D layout col = lane&15, row = (lane>>4)*4 + reg
    const float scale = sum[0] * (1.0f / (float)((size_t)NDIM * KDIM));
    const int r0w = (lane >> 4) << 2;
    const int cB = n0 + wc * 64 + (lane & 15);
    #pragma unroll
    for (int m = 0; m < 8; ++m) {
        #pragma unroll
        for (int r = 0; r < 4; ++r) {
            const int row = m0 + wr * 128 + m * 16 + r0w + r;
            float* crow = C + (size_t)row * NDIM + cB;
            #pragma unroll
            for (int nn = 0; nn < 4; ++nn)
                crow[nn * 16] = acc[m][nn][r] * scale;
        }
    }
}

extern "C" void kernel_launch(void* const* d_in, const int* in_sizes, int n_in,
                              void* d_out, int out_size, void* d_ws, size_t ws_size,
                              hipStream_t stream) {
    const float* x = (const float*)d_in[0];   // 8192 x 4096 fp32
    const float* w = (const float*)d_in[1];   // 4096 x 4096 fp32
    float* out = (float*)d_out;               // 8192 x 4096 fp32

    // workspace layout: [x_bf16: 67,108,864 B][signW_bf16: 33,554,432 B][sum: 4 B]
    unsigned short* xb = (unsigned short*)d_ws;
    unsigned short* wb = (unsigned short*)((char*)d_ws + (size_t)MDIM * KDIM * 2);
    float* sum = (float*)((char*)d_ws + (size_t)MDIM * KDIM * 2 + (size_t)NDIM * KDIM * 2);

    hipMemsetAsync(sum, 0, sizeof(float), stream);  // ws is poisoned 0xAA each run
    cvt_x_kernel<<<2048, 256, 0, stream>>>(x, xb);
    cvt_w_kernel<<<2048, 256, 0, stream>>>(w, wb, sum);

    gemm_kernel<<<dim3(512), dim3(512), 0, stream>>>(xb, wb, out, sum);
}